// Round 14
// baseline (346.420 us; speedup 1.0000x reference)
//
#include <hip/hip_runtime.h>

#define EMB 768
#define NK  8192
#define NB  16384
#define MARGIN 0.010f  // COSINE units: r12-validated (>= 2*8sigma i8 err + bm16 rounding)
#define CAP  2048      // per-block candidate list capacity

typedef __attribute__((ext_vector_type(4))) int   i32x4;
typedef __attribute__((ext_vector_type(4))) float f32x4;

// ---------------- helpers ----------------
__device__ __forceinline__ unsigned short f2bf(float f){
  unsigned u = __float_as_uint(f);
  u += 0x7FFFu + ((u >> 16) & 1u);
  return (unsigned short)(u >> 16);
}
__device__ __forceinline__ float bf2f(unsigned short b){
  return __uint_as_float(((unsigned)b) << 16);
}
__device__ __forceinline__ unsigned fenc(float v){
  unsigned u = __float_as_uint(v);
  return (u & 0x80000000u) ? ~u : (u | 0x80000000u);
}
__device__ __forceinline__ int q8(float v, float qs){
  int a = (int)rintf(v * qs);
  return a > 127 ? 127 : (a < -127 ? -127 : a);
}
__device__ __forceinline__ unsigned pack4(float4 v, float qs){
  return (unsigned)(q8(v.x,qs) & 255) | ((unsigned)(q8(v.y,qs) & 255) << 8) |
         ((unsigned)(q8(v.z,qs) & 255) << 16) | ((unsigned)(q8(v.w,qs) & 255) << 24);
}

// ---------------- fused prep: normalize+quantize X and Cb to i8, init state --
__global__ __launch_bounds__(256)
void prep_k(const float* __restrict__ X, const float* __restrict__ C,
            unsigned char* __restrict__ Xq, unsigned char* __restrict__ Cq,
            float* __restrict__ sx, float* __restrict__ sc, float* __restrict__ rn,
            unsigned long long* __restrict__ keys, int* __restrict__ cnt){
  const int bid = blockIdx.x;
  const int tid = threadIdx.x;
  const int lane = tid & 63;
  if (bid < NB / 4){
    const int r = bid * 4 + (tid >> 6);
    const float4* x4 = (const float4*)(X + (size_t)r * EMB);
    const float4 v0 = x4[lane], v1 = x4[lane + 64], v2 = x4[lane + 128];
    float ss = 0.f, mx = 0.f;
    ss = fmaf(v0.x,v0.x,fmaf(v0.y,v0.y,fmaf(v0.z,v0.z,fmaf(v0.w,v0.w,ss))));
    ss = fmaf(v1.x,v1.x,fmaf(v1.y,v1.y,fmaf(v1.z,v1.z,fmaf(v1.w,v1.w,ss))));
    ss = fmaf(v2.x,v2.x,fmaf(v2.y,v2.y,fmaf(v2.z,v2.z,fmaf(v2.w,v2.w,ss))));
    mx = fmaxf(fmaxf(fmaxf(fabsf(v0.x),fabsf(v0.y)),fmaxf(fabsf(v0.z),fabsf(v0.w))), mx);
    mx = fmaxf(fmaxf(fmaxf(fabsf(v1.x),fabsf(v1.y)),fmaxf(fabsf(v1.z),fabsf(v1.w))), mx);
    mx = fmaxf(fmaxf(fmaxf(fabsf(v2.x),fabsf(v2.y)),fmaxf(fabsf(v2.z),fabsf(v2.w))), mx);
    #pragma unroll
    for (int off = 1; off < 64; off <<= 1){
      ss += __shfl_xor(ss, off);
      mx = fmaxf(mx, __shfl_xor(mx, off));
    }
    const float norm = sqrtf(ss);
    const float qs = 127.0f / fmaxf(mx, 1e-20f);
    unsigned* oq = (unsigned*)(Xq + (size_t)r * EMB);
    oq[lane]       = pack4(v0, qs);
    oq[lane + 64]  = pack4(v1, qs);
    oq[lane + 128] = pack4(v2, qs);
    if (lane == 0){
      sx[r] = mx / (127.0f * fmaxf(norm, 1e-8f));
      keys[r] = 0ull;
    }
    if (lane == 1 && r < 512) cnt[r] = 0;
  } else {
    const int r = (bid - NB / 4) * 4 + (tid >> 6);
    const float4* c4 = (const float4*)(C + (size_t)r * EMB);
    const float4 v0 = c4[lane], v1 = c4[lane + 64], v2 = c4[lane + 128];
    float ss = 0.f, mx = 0.f;
    ss = fmaf(v0.x,v0.x,fmaf(v0.y,v0.y,fmaf(v0.z,v0.z,fmaf(v0.w,v0.w,ss))));
    ss = fmaf(v1.x,v1.x,fmaf(v1.y,v1.y,fmaf(v1.z,v1.z,fmaf(v1.w,v1.w,ss))));
    ss = fmaf(v2.x,v2.x,fmaf(v2.y,v2.y,fmaf(v2.z,v2.z,fmaf(v2.w,v2.w,ss))));
    mx = fmaxf(fmaxf(fmaxf(fabsf(v0.x),fabsf(v0.y)),fmaxf(fabsf(v0.z),fabsf(v0.w))), mx);
    mx = fmaxf(fmaxf(fmaxf(fabsf(v1.x),fabsf(v1.y)),fmaxf(fabsf(v1.z),fabsf(v1.w))), mx);
    mx = fmaxf(fmaxf(fmaxf(fabsf(v2.x),fabsf(v2.y)),fmaxf(fabsf(v2.z),fabsf(v2.w))), mx);
    #pragma unroll
    for (int off = 1; off < 64; off <<= 1){
      ss += __shfl_xor(ss, off);
      mx = fmaxf(mx, __shfl_xor(mx, off));
    }
    const float norm = sqrtf(ss);
    const float qs = 127.0f / fmaxf(mx, 1e-20f);
    unsigned* oq = (unsigned*)(Cq + (size_t)r * EMB);
    oq[lane]       = pack4(v0, qs);
    oq[lane + 64]  = pack4(v1, qs);
    oq[lane + 128] = pack4(v2, qs);
    if (lane == 0){
      sc[r] = mx / (127.0f * fmaxf(norm, 1e-8f));
      rn[r] = 1.0f / fmaxf(norm, 1e-8f);
    }
  }
}

// ---------------- i8 MFMA GEMM (2-phase double-buffered) -> 16-col blockmax --
// T3 minimum recipe with r12's PROVEN staging addressing (4 x 1KB per wave,
// wave-uniform LDS dest, source-side XOR swizzle). One vmcnt(0)+barrier per tile.
__global__ __launch_bounds__(256, 2)
void gemm_bmax_k(const unsigned char* __restrict__ Xq, const unsigned char* __restrict__ Cq,
                 const float* __restrict__ sx, const float* __restrict__ sc,
                 unsigned short* __restrict__ bm16){
  __shared__ __align__(16) char lds[65536];   // [buf][A 16KB | B 16KB]
  const int tid  = threadIdx.x;
  const int lane = tid & 63;
  const int w    = tid >> 6;
  const int wm   = w >> 1, wn = w & 1;

  // XCD-aware: m partitioned per XCD (A-panel L2-resident), n slow
  const int bid = blockIdx.x;
  const int xcd = bid & 7;
  const int kb  = bid >> 3;
  const int m0  = (xcd * 16 + (kb & 15)) * 128;
  const int n0  = (kb >> 4) * 128;

  // per-thread staging SOURCE pointers (swizzle pre-applied), exactly as r12
  const unsigned char* gAp[4];
  const unsigned char* gBp[4];
  #pragma unroll
  for (int i = 0; i < 4; ++i){
    const int base = w * 4096 + i * 1024;
    const int L    = base + lane * 16;
    const int row  = L >> 7;
    const int sc_  = (L & 127) ^ ((row & 7) << 4);
    gAp[i] = Xq + (size_t)(m0 + row) * EMB + sc_;
    gBp[i] = Cq + (size_t)(n0 + row) * EMB + sc_;
  }

#define STAGE_TILE(bufoff_, k0_) do{ \
    _Pragma("unroll") \
    for (int i_ = 0; i_ < 4; ++i_){ \
      const int dbase_ = (bufoff_) + w * 4096 + i_ * 1024; \
      __builtin_amdgcn_global_load_lds((const __attribute__((address_space(1))) void*)(gAp[i_] + (k0_)), \
          (__attribute__((address_space(3))) void*)(lds + dbase_), 16, 0, 0); \
      __builtin_amdgcn_global_load_lds((const __attribute__((address_space(1))) void*)(gBp[i_] + (k0_)), \
          (__attribute__((address_space(3))) void*)(lds + 16384 + dbase_), 16, 0, 0); \
    } \
  }while(0)

  i32x4 acc[4][4];
  #pragma unroll
  for (int m = 0; m < 4; ++m)
    #pragma unroll
    for (int n = 0; n < 4; ++n)
      acc[m][n] = (i32x4){0, 0, 0, 0};

  // prologue: tile 0 -> buf 0, drain, barrier
  STAGE_TILE(0, 0);
  asm volatile("s_waitcnt vmcnt(0)" ::: "memory");
  __builtin_amdgcn_s_barrier();

  int cur = 0;
  for (int kt = 0; kt < 6; ++kt){
    const int coff = cur ? 32768 : 0;
    if (kt < 5) STAGE_TILE(coff ^ 32768, (kt + 1) * 128);   // prefetch next tile
    const char* As = lds + coff;
    const char* Bs = As + 16384;
    #pragma unroll
    for (int kk = 0; kk < 2; ++kk){
      i32x4 a[4], b[4];
      const int cb = kk * 64 + ((lane >> 4) << 4);
      #pragma unroll
      for (int m = 0; m < 4; ++m){
        const int rl = wm * 64 + m * 16 + (lane & 15);
        a[m] = *(const i32x4*)(As + rl * 128 + (cb ^ ((rl & 7) << 4)));
      }
      #pragma unroll
      for (int n = 0; n < 4; ++n){
        const int rl = wn * 64 + n * 16 + (lane & 15);
        b[n] = *(const i32x4*)(Bs + rl * 128 + (cb ^ ((rl & 7) << 4)));
      }
      #pragma unroll
      for (int m = 0; m < 4; ++m)
        #pragma unroll
        for (int n = 0; n < 4; ++n)
          acc[m][n] = __builtin_amdgcn_mfma_i32_16x16x64_i8(a[m], b[n], acc[m][n], 0, 0, 0);
    }
    asm volatile("s_waitcnt vmcnt(0)" ::: "memory");  // prefetched tile landed
    __builtin_amdgcn_s_barrier();                     // all waves done reading cur
    cur ^= 1;
  }
#undef STAGE_TILE

  // epilogue: sim = acc * sc[col] * sx[row]; per-16col maxes; bf16 store
  float scv[4];
  #pragma unroll
  for (int n = 0; n < 4; ++n)
    scv[n] = sc[n0 + wn * 64 + n * 16 + (lane & 15)];
  const int rbase = m0 + wm * 64 + ((lane >> 4) << 2);
  const int blk0  = (n0 >> 4) + wn * 4;
  #pragma unroll
  for (int m = 0; m < 4; ++m){
    #pragma unroll
    for (int rg = 0; rg < 4; ++rg){
      const int row = rbase + m * 16 + rg;
      const float sxr = sx[row];
      const float s0 = (float)acc[m][0][rg] * scv[0] * sxr;
      const float s1 = (float)acc[m][1][rg] * scv[1] * sxr;
      const float s2 = (float)acc[m][2][rg] * scv[2] * sxr;
      const float s3 = (float)acc[m][3][rg] * scv[3] * sxr;
      const float a  = (lane & 1) ? s0 : s1;
      const float b  = (lane & 1) ? s2 : s3;
      const float ra = __shfl_xor(a, 1);
      const float rb = __shfl_xor(b, 1);
      const float u  = (lane & 1) ? fmaxf(s1, ra) : fmaxf(s0, ra);
      const float v  = (lane & 1) ? fmaxf(s3, rb) : fmaxf(s2, rb);
      const float c  = (lane & 2) ? u : v;
      const float rc = __shfl_xor(c, 2);
      float wv = fmaxf((lane & 2) ? v : u, rc);
      wv = fmaxf(wv, __shfl_xor(wv, 4));
      wv = fmaxf(wv, __shfl_xor(wv, 8));
      if ((lane & 15) < 4){
        bm16[(size_t)row * 512 + blk0 + (lane & 3)] = f2bf(wv);
      }
    }
  }
}

// ---------------- per-row candidate extraction -> per-block row lists --------
__global__ __launch_bounds__(256)
void cand_k(const unsigned short* __restrict__ bm16, int* __restrict__ cnt,
            int* __restrict__ list){
  const int r    = blockIdx.x * 4 + (threadIdx.x >> 6);
  const int lane = threadIdx.x & 63;
  const ushort4 q0 = ((const ushort4*)(bm16 + (size_t)r * 512))[lane];
  const ushort4 q1 = ((const ushort4*)(bm16 + (size_t)r * 512))[lane + 64];
  float v[8];
  v[0]=bf2f(q0.x); v[1]=bf2f(q0.y); v[2]=bf2f(q0.z); v[3]=bf2f(q0.w);
  v[4]=bf2f(q1.x); v[5]=bf2f(q1.y); v[6]=bf2f(q1.z); v[7]=bf2f(q1.w);
  float m = v[0];
  #pragma unroll
  for (int k = 1; k < 8; ++k) m = fmaxf(m, v[k]);
  #pragma unroll
  for (int off = 1; off < 64; off <<= 1) m = fmaxf(m, __shfl_xor(m, off));
  const float thr = m - MARGIN;
  #pragma unroll
  for (int k = 0; k < 8; ++k){
    if (v[k] >= thr){
      const int blk = (k < 4) ? (lane * 4 + k) : ((lane + 64) * 4 + (k - 4));
      const int s = atomicAdd(&cnt[blk], 1);
      if (s < CAP) list[blk * CAP + s] = r;
    }
  }
}

// ---------------- codebook-stationary fp32 rescore from lists ----------------
__global__ __launch_bounds__(256, 2)
void rescore_k(const float* __restrict__ X, const float* __restrict__ Cb,
               const float* __restrict__ rn, const int* __restrict__ cnt,
               const int* __restrict__ list, unsigned long long* __restrict__ keys){
  __shared__ float cbs[16 * EMB];   // 48 KB
  __shared__ float rns[16];
  const int g    = blockIdx.x >> 1;      // 16-col block 0..511
  const int half = blockIdx.x & 1;
  const int tid = threadIdx.x;
  const int lane = tid & 63;
  const int w = tid >> 6;

  for (int i = tid; i < 16 * EMB / 4; i += 256)
    ((float4*)cbs)[i] = ((const float4*)(Cb + (size_t)g * 16 * EMB))[i];
  if (tid < 16) rns[tid] = rn[g * 16 + tid];
  __syncthreads();

  const int nc = min(cnt[g], CAP);
  const float4* cbs4 = (const float4*)cbs;
  for (int ci = half * 4 + w; ci < nc; ci += 8){
    const int r = list[g * CAP + ci];
    const float4* x4 = (const float4*)(X + (size_t)r * EMB);
    const float4 x0 = x4[lane], x1 = x4[lane + 64], x2 = x4[lane + 128];
    float best = -3.0e38f; int bc = 0;
    #pragma unroll
    for (int c = 0; c < 16; ++c){
      const float4 c0 = cbs4[c * 192 + lane];
      const float4 c1 = cbs4[c * 192 + lane + 64];
      const float4 c2 = cbs4[c * 192 + lane + 128];
      float s = 0.f;
      s = fmaf(x0.x, c0.x, s); s = fmaf(x0.y, c0.y, s);
      s = fmaf(x0.z, c0.z, s); s = fmaf(x0.w, c0.w, s);
      s = fmaf(x1.x, c1.x, s); s = fmaf(x1.y, c1.y, s);
      s = fmaf(x1.z, c1.z, s); s = fmaf(x1.w, c1.w, s);
      s = fmaf(x2.x, c2.x, s); s = fmaf(x2.y, c2.y, s);
      s = fmaf(x2.z, c2.z, s); s = fmaf(x2.w, c2.w, s);
      #pragma unroll
      for (int off = 1; off < 64; off <<= 1) s += __shfl_xor(s, off);
      s *= rns[c];
      if (s > best){ best = s; bc = c; }     // strict > : first index within block
    }
    if (lane == 0){
      const int col = g * 16 + bc;
      const unsigned long long key =
          ((unsigned long long)fenc(best) << 32) | (unsigned)(8191 - col);
      atomicMax(&keys[r], key);
    }
  }
}

// ---------------- gather + output + per-row loss (one wave per row) ----------
__global__ __launch_bounds__(256)
void writer_k(const float* __restrict__ X, const float* __restrict__ Cb,
              const unsigned long long* __restrict__ keys,
              float* __restrict__ out, float* __restrict__ rowloss){
  const int r    = (blockIdx.x * 256 + threadIdx.x) >> 6;   // one wave per row
  const int lane = threadIdx.x & 63;
  const int idx = 8191 - (int)(unsigned)(keys[r] & 0xFFFFFFFFull);
  const float4* q = (const float4*)(Cb + (size_t)idx * EMB);
  const float4* x = (const float4*)(X + (size_t)r * EMB);
  float4* o = (float4*)(out + (size_t)r * EMB);
  float s = 0.f;
  #pragma unroll
  for (int j = 0; j < 3; ++j){
    const float4 qv = q[lane + 64 * j];
    const float4 xv = x[lane + 64 * j];
    float4 ov;
    float dx = qv.x - xv.x, dy = qv.y - xv.y, dz = qv.z - xv.z, dw = qv.w - xv.w;
    ov.x = xv.x + dx; ov.y = xv.y + dy; ov.z = xv.z + dz; ov.w = xv.w + dw;
    o[lane + 64 * j] = ov;
    s = fmaf(dx, dx, fmaf(dy, dy, fmaf(dz, dz, fmaf(dw, dw, s))));
  }
  #pragma unroll
  for (int off = 1; off < 64; off <<= 1) s += __shfl_xor(s, off);
  if (lane == 0) rowloss[r] = s;
}

// ---------------- deterministic loss finalize (1024 threads) ----------------
__global__ __launch_bounds__(1024)
void finalize_k(const float* __restrict__ rowloss, float* __restrict__ loss_out){
  __shared__ double red[1024];
  const int tid = threadIdx.x;
  double s = 0.0;
  for (int i = tid; i < NB; i += 1024) s += (double)rowloss[i];
  red[tid] = s; __syncthreads();
  for (int off = 512; off > 0; off >>= 1){
    if (tid < off) red[tid] += red[tid + off];
    __syncthreads();
  }
  if (tid == 0)
    loss_out[0] = (float)(1.25 * red[0] / ((double)NB * (double)EMB));
}

extern "C" void kernel_launch(void* const* d_in, const int* in_sizes, int n_in,
                              void* d_out, int out_size, void* d_ws, size_t ws_size,
                              hipStream_t stream){
  const float* X  = (const float*)d_in[0];
  const float* Cb = (const float*)d_in[1];
  float* out = (float*)d_out;

  // i8 staging copies live inside d_out (fully rewritten by writer_k later)
  unsigned char* Xq = (unsigned char*)d_out;                             // 12.6 MB
  unsigned char* Cq = (unsigned char*)d_out + (size_t)NB * EMB;          //  6.3 MB

  char* ws = (char*)d_ws;
  unsigned short* bm16 = (unsigned short*)ws;                          // 16.8 MB
  char* p = ws + (size_t)NB * 512 * 2;
  int* cnt  = (int*)p;                         p += 512 * 4;           // 2 KB
  int* list = (int*)p;                         p += (size_t)512 * CAP * 4; // 4 MB
  unsigned long long* keys = (unsigned long long*)p; p += (size_t)NB * 8;  // 128 KB
  float* rn      = (float*)p;                  p += (size_t)NK * 4;    // 32 KB
  float* rowloss = (float*)p;                  p += (size_t)NB * 4;    // 64 KB
  float* sx      = (float*)p;                  p += (size_t)NB * 4;    // 64 KB
  float* sc      = (float*)p;                                          // 32 KB

  prep_k<<<NB / 4 + NK / 4, 256, 0, stream>>>(X, Cb, Xq, Cq, sx, sc, rn, keys, cnt);
  gemm_bmax_k<<<8192, 256, 0, stream>>>(Xq, Cq, sx, sc, bm16);
  cand_k<<<NB / 4, 256, 0, stream>>>(bm16, cnt, list);
  rescore_k<<<1024, 256, 0, stream>>>(X, Cb, rn, cnt, list, keys);
  writer_k<<<NB / 4, 256, 0, stream>>>(X, Cb, keys, out, rowloss);
  finalize_k<<<1, 1024, 0, stream>>>(rowloss, out + (size_t)NB * EMB);
}

// Round 15
// 323.290 us; speedup vs baseline: 1.0715x; 1.0715x over previous
//
#include <hip/hip_runtime.h>

#define EMB 768
#define NK  8192
#define NB  16384
#define MARGIN 0.010f  // COSINE units: r12-validated (>= 2*8sigma i8 err + bm16 rounding)
#define CAP  2048      // per-block candidate list capacity

typedef __attribute__((ext_vector_type(4))) int   i32x4;
typedef __attribute__((ext_vector_type(4))) float f32x4;

// ---------------- helpers ----------------
__device__ __forceinline__ unsigned short f2bf(float f){
  unsigned u = __float_as_uint(f);
  u += 0x7FFFu + ((u >> 16) & 1u);
  return (unsigned short)(u >> 16);
}
__device__ __forceinline__ float bf2f(unsigned short b){
  return __uint_as_float(((unsigned)b) << 16);
}
__device__ __forceinline__ unsigned fenc(float v){
  unsigned u = __float_as_uint(v);
  return (u & 0x80000000u) ? ~u : (u | 0x80000000u);
}
__device__ __forceinline__ int q8(float v, float qs){
  int a = (int)rintf(v * qs);
  return a > 127 ? 127 : (a < -127 ? -127 : a);
}
__device__ __forceinline__ unsigned pack4(float4 v, float qs){
  return (unsigned)(q8(v.x,qs) & 255) | ((unsigned)(q8(v.y,qs) & 255) << 8) |
         ((unsigned)(q8(v.z,qs) & 255) << 16) | ((unsigned)(q8(v.w,qs) & 255) << 24);
}

// ---------------- fused prep: normalize+quantize X and Cb to i8, init state --
__global__ __launch_bounds__(256)
void prep_k(const float* __restrict__ X, const float* __restrict__ C,
            unsigned char* __restrict__ Xq, unsigned char* __restrict__ Cq,
            float* __restrict__ sx, float* __restrict__ sc, float* __restrict__ rn,
            unsigned long long* __restrict__ keys, int* __restrict__ cnt){
  const int bid = blockIdx.x;
  const int tid = threadIdx.x;
  const int lane = tid & 63;
  if (bid < NB / 4){
    const int r = bid * 4 + (tid >> 6);
    const float4* x4 = (const float4*)(X + (size_t)r * EMB);
    const float4 v0 = x4[lane], v1 = x4[lane + 64], v2 = x4[lane + 128];
    float ss = 0.f, mx = 0.f;
    ss = fmaf(v0.x,v0.x,fmaf(v0.y,v0.y,fmaf(v0.z,v0.z,fmaf(v0.w,v0.w,ss))));
    ss = fmaf(v1.x,v1.x,fmaf(v1.y,v1.y,fmaf(v1.z,v1.z,fmaf(v1.w,v1.w,ss))));
    ss = fmaf(v2.x,v2.x,fmaf(v2.y,v2.y,fmaf(v2.z,v2.z,fmaf(v2.w,v2.w,ss))));
    mx = fmaxf(fmaxf(fmaxf(fabsf(v0.x),fabsf(v0.y)),fmaxf(fabsf(v0.z),fabsf(v0.w))), mx);
    mx = fmaxf(fmaxf(fmaxf(fabsf(v1.x),fabsf(v1.y)),fmaxf(fabsf(v1.z),fabsf(v1.w))), mx);
    mx = fmaxf(fmaxf(fmaxf(fabsf(v2.x),fabsf(v2.y)),fmaxf(fabsf(v2.z),fabsf(v2.w))), mx);
    #pragma unroll
    for (int off = 1; off < 64; off <<= 1){
      ss += __shfl_xor(ss, off);
      mx = fmaxf(mx, __shfl_xor(mx, off));
    }
    const float norm = sqrtf(ss);
    const float qs = 127.0f / fmaxf(mx, 1e-20f);
    unsigned* oq = (unsigned*)(Xq + (size_t)r * EMB);
    oq[lane]       = pack4(v0, qs);
    oq[lane + 64]  = pack4(v1, qs);
    oq[lane + 128] = pack4(v2, qs);
    if (lane == 0){
      sx[r] = mx / (127.0f * fmaxf(norm, 1e-8f));
      keys[r] = 0ull;
    }
    if (lane == 1 && r < 512) cnt[r] = 0;
  } else {
    const int r = (bid - NB / 4) * 4 + (tid >> 6);
    const float4* c4 = (const float4*)(C + (size_t)r * EMB);
    const float4 v0 = c4[lane], v1 = c4[lane + 64], v2 = c4[lane + 128];
    float ss = 0.f, mx = 0.f;
    ss = fmaf(v0.x,v0.x,fmaf(v0.y,v0.y,fmaf(v0.z,v0.z,fmaf(v0.w,v0.w,ss))));
    ss = fmaf(v1.x,v1.x,fmaf(v1.y,v1.y,fmaf(v1.z,v1.z,fmaf(v1.w,v1.w,ss))));
    ss = fmaf(v2.x,v2.x,fmaf(v2.y,v2.y,fmaf(v2.z,v2.z,fmaf(v2.w,v2.w,ss))));
    mx = fmaxf(fmaxf(fmaxf(fabsf(v0.x),fabsf(v0.y)),fmaxf(fabsf(v0.z),fabsf(v0.w))), mx);
    mx = fmaxf(fmaxf(fmaxf(fabsf(v1.x),fabsf(v1.y)),fmaxf(fabsf(v1.z),fabsf(v1.w))), mx);
    mx = fmaxf(fmaxf(fmaxf(fabsf(v2.x),fabsf(v2.y)),fmaxf(fabsf(v2.z),fabsf(v2.w))), mx);
    #pragma unroll
    for (int off = 1; off < 64; off <<= 1){
      ss += __shfl_xor(ss, off);
      mx = fmaxf(mx, __shfl_xor(mx, off));
    }
    const float norm = sqrtf(ss);
    const float qs = 127.0f / fmaxf(mx, 1e-20f);
    unsigned* oq = (unsigned*)(Cq + (size_t)r * EMB);
    oq[lane]       = pack4(v0, qs);
    oq[lane + 64]  = pack4(v1, qs);
    oq[lane + 128] = pack4(v2, qs);
    if (lane == 0){
      sc[r] = mx / (127.0f * fmaxf(norm, 1e-8f));
      rn[r] = 1.0f / fmaxf(norm, 1e-8f);
    }
  }
}

// ---------------- i8 MFMA GEMM (128x256 tile, 8x4 frags/wave) -> blockmax ----
// Single-buffer r12 schedule (stage -> syncthreads -> compute -> syncthreads).
// 4 waves side-by-side in n; each wave = 128x64 out (8 m-frags x 4 n-frags)
// -> 12 ds_read per kk for 32 MFMA (intensity 43690 MAC/read vs r12's 32768).
__global__ __launch_bounds__(256, 2)
void gemm_bmax_k(const unsigned char* __restrict__ Xq, const unsigned char* __restrict__ Cq,
                 const float* __restrict__ sx, const float* __restrict__ sc,
                 unsigned short* __restrict__ bm16){
  __shared__ __align__(16) char lds[49152];   // As 16KB (128x128B) | Bs 32KB (256x128B)
  char* As = lds;
  char* Bs = lds + 16384;
  const int tid  = threadIdx.x;
  const int lane = tid & 63;
  const int w    = tid >> 6;          // wave = n-slot 0..3

  // XCD-aware: m partitioned per XCD (A-panel 1.5MB L2-resident), n slow
  const int bid = blockIdx.x;
  const int xcd = bid & 7;
  const int kb  = bid >> 3;                    // 0..511
  const int m0  = (xcd * 16 + (kb & 15)) * 128;
  const int n0  = (kb >> 4) * 256;

  // staging source pointers (source-side XOR swizzle, wave-uniform LDS dests)
  const unsigned char* gAp[4];
  const unsigned char* gBp[8];
  #pragma unroll
  for (int j = 0; j < 4; ++j){
    const int L   = w * 4096 + j * 1024 + lane * 16;
    const int row = L >> 7;                    // 0..127
    const int col = (L & 127) ^ ((row & 7) << 4);
    gAp[j] = Xq + (size_t)(m0 + row) * EMB + col;
  }
  #pragma unroll
  for (int j = 0; j < 8; ++j){
    const int L   = w * 8192 + j * 1024 + lane * 16;
    const int row = L >> 7;                    // 0..255
    const int col = (L & 127) ^ ((row & 7) << 4);
    gBp[j] = Cq + (size_t)(n0 + row) * EMB + col;
  }

  i32x4 acc[8][4];
  #pragma unroll
  for (int m = 0; m < 8; ++m)
    #pragma unroll
    for (int n = 0; n < 4; ++n)
      acc[m][n] = (i32x4){0, 0, 0, 0};

  for (int kt = 0; kt < 6; ++kt){
    const int k0 = kt * 128;                   // byte offset within row
    #pragma unroll
    for (int j = 0; j < 4; ++j)
      __builtin_amdgcn_global_load_lds((const __attribute__((address_space(1))) void*)(gAp[j] + k0),
          (__attribute__((address_space(3))) void*)(As + w * 4096 + j * 1024), 16, 0, 0);
    #pragma unroll
    for (int j = 0; j < 8; ++j)
      __builtin_amdgcn_global_load_lds((const __attribute__((address_space(1))) void*)(gBp[j] + k0),
          (__attribute__((address_space(3))) void*)(Bs + w * 8192 + j * 1024), 16, 0, 0);
    __syncthreads();
    #pragma unroll
    for (int kk = 0; kk < 2; ++kk){
      i32x4 a[8], b[4];
      const int cb = kk * 64 + ((lane >> 4) << 4);
      #pragma unroll
      for (int m = 0; m < 8; ++m){
        const int rl = m * 16 + (lane & 15);               // rows 0..127
        a[m] = *(const i32x4*)(As + rl * 128 + (cb ^ ((rl & 7) << 4)));
      }
      #pragma unroll
      for (int n = 0; n < 4; ++n){
        const int rl = w * 64 + n * 16 + (lane & 15);      // rows 0..255
        b[n] = *(const i32x4*)(Bs + rl * 128 + (cb ^ ((rl & 7) << 4)));
      }
      #pragma unroll
      for (int m = 0; m < 8; ++m)
        #pragma unroll
        for (int n = 0; n < 4; ++n)
          acc[m][n] = __builtin_amdgcn_mfma_i32_16x16x64_i8(a[m], b[n], acc[m][n], 0, 0, 0);
    }
    __syncthreads();
  }

  // epilogue: sim = acc * sc[col] * sx[row]; per-16col maxes; bf16 store
  float scv[4];
  #pragma unroll
  for (int n = 0; n < 4; ++n)
    scv[n] = sc[n0 + w * 64 + n * 16 + (lane & 15)];
  const int rbase = m0 + ((lane >> 4) << 2);
  const int blk0  = (n0 >> 4) + w * 4;
  #pragma unroll
  for (int m = 0; m < 8; ++m){
    #pragma unroll
    for (int rg = 0; rg < 4; ++rg){
      const int row = rbase + m * 16 + rg;
      const float sxr = sx[row];
      const float s0 = (float)acc[m][0][rg] * scv[0] * sxr;
      const float s1 = (float)acc[m][1][rg] * scv[1] * sxr;
      const float s2 = (float)acc[m][2][rg] * scv[2] * sxr;
      const float s3 = (float)acc[m][3][rg] * scv[3] * sxr;
      const float a  = (lane & 1) ? s0 : s1;
      const float b  = (lane & 1) ? s2 : s3;
      const float ra = __shfl_xor(a, 1);
      const float rb = __shfl_xor(b, 1);
      const float u  = (lane & 1) ? fmaxf(s1, ra) : fmaxf(s0, ra);
      const float v  = (lane & 1) ? fmaxf(s3, rb) : fmaxf(s2, rb);
      const float c  = (lane & 2) ? u : v;
      const float rc = __shfl_xor(c, 2);
      float wv = fmaxf((lane & 2) ? v : u, rc);
      wv = fmaxf(wv, __shfl_xor(wv, 4));
      wv = fmaxf(wv, __shfl_xor(wv, 8));
      if ((lane & 15) < 4){
        bm16[(size_t)row * 512 + blk0 + (lane & 3)] = f2bf(wv);
      }
    }
  }
}

// ---------------- per-row candidate extraction -> per-block row lists --------
__global__ __launch_bounds__(256)
void cand_k(const unsigned short* __restrict__ bm16, int* __restrict__ cnt,
            int* __restrict__ list){
  const int r    = blockIdx.x * 4 + (threadIdx.x >> 6);
  const int lane = threadIdx.x & 63;
  const ushort4 q0 = ((const ushort4*)(bm16 + (size_t)r * 512))[lane];
  const ushort4 q1 = ((const ushort4*)(bm16 + (size_t)r * 512))[lane + 64];
  float v[8];
  v[0]=bf2f(q0.x); v[1]=bf2f(q0.y); v[2]=bf2f(q0.z); v[3]=bf2f(q0.w);
  v[4]=bf2f(q1.x); v[5]=bf2f(q1.y); v[6]=bf2f(q1.z); v[7]=bf2f(q1.w);
  float m = v[0];
  #pragma unroll
  for (int k = 1; k < 8; ++k) m = fmaxf(m, v[k]);
  #pragma unroll
  for (int off = 1; off < 64; off <<= 1) m = fmaxf(m, __shfl_xor(m, off));
  const float thr = m - MARGIN;
  #pragma unroll
  for (int k = 0; k < 8; ++k){
    if (v[k] >= thr){
      const int blk = (k < 4) ? (lane * 4 + k) : ((lane + 64) * 4 + (k - 4));
      const int s = atomicAdd(&cnt[blk], 1);
      if (s < CAP) list[blk * CAP + s] = r;
    }
  }
}

// ---------------- codebook-stationary fp32 rescore from lists ----------------
__global__ __launch_bounds__(256, 2)
void rescore_k(const float* __restrict__ X, const float* __restrict__ Cb,
               const float* __restrict__ rn, const int* __restrict__ cnt,
               const int* __restrict__ list, unsigned long long* __restrict__ keys){
  __shared__ float cbs[16 * EMB];   // 48 KB
  __shared__ float rns[16];
  const int g    = blockIdx.x >> 1;      // 16-col block 0..511
  const int half = blockIdx.x & 1;
  const int tid = threadIdx.x;
  const int lane = tid & 63;
  const int w = tid >> 6;

  for (int i = tid; i < 16 * EMB / 4; i += 256)
    ((float4*)cbs)[i] = ((const float4*)(Cb + (size_t)g * 16 * EMB))[i];
  if (tid < 16) rns[tid] = rn[g * 16 + tid];
  __syncthreads();

  const int nc = min(cnt[g], CAP);
  const float4* cbs4 = (const float4*)cbs;
  for (int ci = half * 4 + w; ci < nc; ci += 8){
    const int r = list[g * CAP + ci];
    const float4* x4 = (const float4*)(X + (size_t)r * EMB);
    const float4 x0 = x4[lane], x1 = x4[lane + 64], x2 = x4[lane + 128];
    float best = -3.0e38f; int bc = 0;
    #pragma unroll
    for (int c = 0; c < 16; ++c){
      const float4 c0 = cbs4[c * 192 + lane];
      const float4 c1 = cbs4[c * 192 + lane + 64];
      const float4 c2 = cbs4[c * 192 + lane + 128];
      float s = 0.f;
      s = fmaf(x0.x, c0.x, s); s = fmaf(x0.y, c0.y, s);
      s = fmaf(x0.z, c0.z, s); s = fmaf(x0.w, c0.w, s);
      s = fmaf(x1.x, c1.x, s); s = fmaf(x1.y, c1.y, s);
      s = fmaf(x1.z, c1.z, s); s = fmaf(x1.w, c1.w, s);
      s = fmaf(x2.x, c2.x, s); s = fmaf(x2.y, c2.y, s);
      s = fmaf(x2.z, c2.z, s); s = fmaf(x2.w, c2.w, s);
      #pragma unroll
      for (int off = 1; off < 64; off <<= 1) s += __shfl_xor(s, off);
      s *= rns[c];
      if (s > best){ best = s; bc = c; }     // strict > : first index within block
    }
    if (lane == 0){
      const int col = g * 16 + bc;
      const unsigned long long key =
          ((unsigned long long)fenc(best) << 32) | (unsigned)(8191 - col);
      atomicMax(&keys[r], key);
    }
  }
}

// ---------------- gather + output + per-row loss (one wave per row) ----------
__global__ __launch_bounds__(256)
void writer_k(const float* __restrict__ X, const float* __restrict__ Cb,
              const unsigned long long* __restrict__ keys,
              float* __restrict__ out, float* __restrict__ rowloss){
  const int r    = (blockIdx.x * 256 + threadIdx.x) >> 6;   // one wave per row
  const int lane = threadIdx.x & 63;
  const int idx = 8191 - (int)(unsigned)(keys[r] & 0xFFFFFFFFull);
  const float4* q = (const float4*)(Cb + (size_t)idx * EMB);
  const float4* x = (const float4*)(X + (size_t)r * EMB);
  float4* o = (float4*)(out + (size_t)r * EMB);
  float s = 0.f;
  #pragma unroll
  for (int j = 0; j < 3; ++j){
    const float4 qv = q[lane + 64 * j];
    const float4 xv = x[lane + 64 * j];
    float4 ov;
    float dx = qv.x - xv.x, dy = qv.y - xv.y, dz = qv.z - xv.z, dw = qv.w - xv.w;
    ov.x = xv.x + dx; ov.y = xv.y + dy; ov.z = xv.z + dz; ov.w = xv.w + dw;
    o[lane + 64 * j] = ov;
    s = fmaf(dx, dx, fmaf(dy, dy, fmaf(dz, dz, fmaf(dw, dw, s))));
  }
  #pragma unroll
  for (int off = 1; off < 64; off <<= 1) s += __shfl_xor(s, off);
  if (lane == 0) rowloss[r] = s;
}

// ---------------- deterministic loss finalize (1024 threads) ----------------
__global__ __launch_bounds__(1024)
void finalize_k(const float* __restrict__ rowloss, float* __restrict__ loss_out){
  __shared__ double red[1024];
  const int tid = threadIdx.x;
  double s = 0.0;
  for (int i = tid; i < NB; i += 1024) s += (double)rowloss[i];
  red[tid] = s; __syncthreads();
  for (int off = 512; off > 0; off >>= 1){
    if (tid < off) red[tid] += red[tid + off];
    __syncthreads();
  }
  if (tid == 0)
    loss_out[0] = (float)(1.25 * red[0] / ((double)NB * (double)EMB));
}

extern "C" void kernel_launch(void* const* d_in, const int* in_sizes, int n_in,
                              void* d_out, int out_size, void* d_ws, size_t ws_size,
                              hipStream_t stream){
  const float* X  = (const float*)d_in[0];
  const float* Cb = (const float*)d_in[1];
  float* out = (float*)d_out;

  // i8 staging copies live inside d_out (fully rewritten by writer_k later)
  unsigned char* Xq = (unsigned char*)d_out;                             // 12.6 MB
  unsigned char* Cq = (unsigned char*)d_out + (size_t)NB * EMB;          //  6.3 MB

  char* ws = (char*)d_ws;
  unsigned short* bm16 = (unsigned short*)ws;                          // 16.8 MB
  char* p = ws + (size_t)NB * 512 * 2;
  int* cnt  = (int*)p;                         p += 512 * 4;           // 2 KB
  int* list = (int*)p;                         p += (size_t)512 * CAP * 4; // 4 MB
  unsigned long long* keys = (unsigned long long*)p; p += (size_t)NB * 8;  // 128 KB
  float* rn      = (float*)p;                  p += (size_t)NK * 4;    // 32 KB
  float* rowloss = (float*)p;                  p += (size_t)NB * 4;    // 64 KB
  float* sx      = (float*)p;                  p += (size_t)NB * 4;    // 64 KB
  float* sc      = (float*)p;                                          // 32 KB

  prep_k<<<NB / 4 + NK / 4, 256, 0, stream>>>(X, Cb, Xq, Cq, sx, sc, rn, keys, cnt);
  gemm_bmax_k<<<4096, 256, 0, stream>>>(Xq, Cq, sx, sc, bm16);
  cand_k<<<NB / 4, 256, 0, stream>>>(bm16, cnt, list);
  rescore_k<<<1024, 256, 0, stream>>>(X, Cb, rn, cnt, list, keys);
  writer_k<<<NB / 4, 256, 0, stream>>>(X, Cb, keys, out, rowloss);
  finalize_k<<<1, 1024, 0, stream>>>(rowloss, out + (size_t)NB * EMB);
}

// Round 16
// 317.860 us; speedup vs baseline: 1.0899x; 1.0171x over previous
//
#include <hip/hip_runtime.h>

#define EMB 768
#define NK  8192
#define NB  16384
#define MARGIN 0.010f  // COSINE units: r12-validated (>= 2*8sigma i8 err + bm16 rounding)
#define CAP  2048      // per-block candidate list capacity

typedef __attribute__((ext_vector_type(4))) int   i32x4;
typedef __attribute__((ext_vector_type(4))) float f32x4;

// ---------------- helpers ----------------
__device__ __forceinline__ unsigned short f2bf(float f){
  unsigned u = __float_as_uint(f);
  u += 0x7FFFu + ((u >> 16) & 1u);
  return (unsigned short)(u >> 16);
}
__device__ __forceinline__ float bf2f(unsigned short b){
  return __uint_as_float(((unsigned)b) << 16);
}
__device__ __forceinline__ unsigned fenc(float v){
  unsigned u = __float_as_uint(v);
  return (u & 0x80000000u) ? ~u : (u | 0x80000000u);
}
__device__ __forceinline__ int q8(float v, float qs){
  int a = (int)rintf(v * qs);
  return a > 127 ? 127 : (a < -127 ? -127 : a);
}
__device__ __forceinline__ unsigned pack4(float4 v, float qs){
  return (unsigned)(q8(v.x,qs) & 255) | ((unsigned)(q8(v.y,qs) & 255) << 8) |
         ((unsigned)(q8(v.z,qs) & 255) << 16) | ((unsigned)(q8(v.w,qs) & 255) << 24);
}

// ---------------- fused prep: normalize+quantize X and Cb to i8, init state --
__global__ __launch_bounds__(256)
void prep_k(const float* __restrict__ X, const float* __restrict__ C,
            unsigned char* __restrict__ Xq, unsigned char* __restrict__ Cq,
            float* __restrict__ sx, float* __restrict__ sc, float* __restrict__ rn,
            unsigned long long* __restrict__ keys, int* __restrict__ cnt){
  const int bid = blockIdx.x;
  const int tid = threadIdx.x;
  const int lane = tid & 63;
  if (bid < NB / 4){
    const int r = bid * 4 + (tid >> 6);
    const float4* x4 = (const float4*)(X + (size_t)r * EMB);
    const float4 v0 = x4[lane], v1 = x4[lane + 64], v2 = x4[lane + 128];
    float ss = 0.f, mx = 0.f;
    ss = fmaf(v0.x,v0.x,fmaf(v0.y,v0.y,fmaf(v0.z,v0.z,fmaf(v0.w,v0.w,ss))));
    ss = fmaf(v1.x,v1.x,fmaf(v1.y,v1.y,fmaf(v1.z,v1.z,fmaf(v1.w,v1.w,ss))));
    ss = fmaf(v2.x,v2.x,fmaf(v2.y,v2.y,fmaf(v2.z,v2.z,fmaf(v2.w,v2.w,ss))));
    mx = fmaxf(fmaxf(fmaxf(fabsf(v0.x),fabsf(v0.y)),fmaxf(fabsf(v0.z),fabsf(v0.w))), mx);
    mx = fmaxf(fmaxf(fmaxf(fabsf(v1.x),fabsf(v1.y)),fmaxf(fabsf(v1.z),fabsf(v1.w))), mx);
    mx = fmaxf(fmaxf(fmaxf(fabsf(v2.x),fabsf(v2.y)),fmaxf(fabsf(v2.z),fabsf(v2.w))), mx);
    #pragma unroll
    for (int off = 1; off < 64; off <<= 1){
      ss += __shfl_xor(ss, off);
      mx = fmaxf(mx, __shfl_xor(mx, off));
    }
    const float norm = sqrtf(ss);
    const float qs = 127.0f / fmaxf(mx, 1e-20f);
    unsigned* oq = (unsigned*)(Xq + (size_t)r * EMB);
    oq[lane]       = pack4(v0, qs);
    oq[lane + 64]  = pack4(v1, qs);
    oq[lane + 128] = pack4(v2, qs);
    if (lane == 0){
      sx[r] = mx / (127.0f * fmaxf(norm, 1e-8f));
      keys[r] = 0ull;
    }
    if (lane == 1 && r < 512) cnt[r] = 0;
  } else {
    const int r = (bid - NB / 4) * 4 + (tid >> 6);
    const float4* c4 = (const float4*)(C + (size_t)r * EMB);
    const float4 v0 = c4[lane], v1 = c4[lane + 64], v2 = c4[lane + 128];
    float ss = 0.f, mx = 0.f;
    ss = fmaf(v0.x,v0.x,fmaf(v0.y,v0.y,fmaf(v0.z,v0.z,fmaf(v0.w,v0.w,ss))));
    ss = fmaf(v1.x,v1.x,fmaf(v1.y,v1.y,fmaf(v1.z,v1.z,fmaf(v1.w,v1.w,ss))));
    ss = fmaf(v2.x,v2.x,fmaf(v2.y,v2.y,fmaf(v2.z,v2.z,fmaf(v2.w,v2.w,ss))));
    mx = fmaxf(fmaxf(fmaxf(fabsf(v0.x),fabsf(v0.y)),fmaxf(fabsf(v0.z),fabsf(v0.w))), mx);
    mx = fmaxf(fmaxf(fmaxf(fabsf(v1.x),fabsf(v1.y)),fmaxf(fabsf(v1.z),fabsf(v1.w))), mx);
    mx = fmaxf(fmaxf(fmaxf(fabsf(v2.x),fabsf(v2.y)),fmaxf(fabsf(v2.z),fabsf(v2.w))), mx);
    #pragma unroll
    for (int off = 1; off < 64; off <<= 1){
      ss += __shfl_xor(ss, off);
      mx = fmaxf(mx, __shfl_xor(mx, off));
    }
    const float norm = sqrtf(ss);
    const float qs = 127.0f / fmaxf(mx, 1e-20f);
    unsigned* oq = (unsigned*)(Cq + (size_t)r * EMB);
    oq[lane]       = pack4(v0, qs);
    oq[lane + 64]  = pack4(v1, qs);
    oq[lane + 128] = pack4(v2, qs);
    if (lane == 0){
      sc[r] = mx / (127.0f * fmaxf(norm, 1e-8f));
      rn[r] = 1.0f / fmaxf(norm, 1e-8f);
    }
  }
}

// ---------------- i8 MFMA GEMM -> 16-col blockmax (bf16, row-major) ----------
// r12 byte-exact: proven 128x128/4-wave/single-buffer structure; K-tile = 128
// i8 bytes (6 tiles); mfma_i32_16x16x64_i8 (2x bf16 MAC rate).
__global__ __launch_bounds__(256, 2)
void gemm_bmax_k(const unsigned char* __restrict__ Xq, const unsigned char* __restrict__ Cq,
                 const float* __restrict__ sx, const float* __restrict__ sc,
                 unsigned short* __restrict__ bm16){
  __shared__ __align__(16) char As[16384];
  __shared__ __align__(16) char Bs[16384];
  const int tid  = threadIdx.x;
  const int lane = tid & 63;
  const int w    = tid >> 6;
  const int wm   = w >> 1, wn = w & 1;

  // XCD-aware: m partitioned per XCD (A-panel L2-resident), n slow
  const int bid = blockIdx.x;
  const int xcd = bid & 7;
  const int kb  = bid >> 3;
  const int m0  = (xcd * 16 + (kb & 15)) * 128;
  const int n0  = (kb >> 4) * 128;

  i32x4 acc[4][4];
  #pragma unroll
  for (int m = 0; m < 4; ++m)
    #pragma unroll
    for (int n = 0; n < 4; ++n)
      acc[m][n] = (i32x4){0, 0, 0, 0};

  for (int kt = 0; kt < 6; ++kt){
    const int k0 = kt * 128;            // byte (=element) offset within row
    #pragma unroll
    for (int i = 0; i < 4; ++i){
      const int base = w * 4096 + i * 1024;
      const int L    = base + lane * 16;
      const int row  = L >> 7;
      const int scol = (L & 127) ^ ((row & 7) << 4);
      const unsigned char* ga = Xq + (size_t)(m0 + row) * EMB + k0 + scol;
      const unsigned char* gb = Cq + (size_t)(n0 + row) * EMB + k0 + scol;
      __builtin_amdgcn_global_load_lds((const __attribute__((address_space(1))) void*)ga,
          (__attribute__((address_space(3))) void*)(As + base), 16, 0, 0);
      __builtin_amdgcn_global_load_lds((const __attribute__((address_space(1))) void*)gb,
          (__attribute__((address_space(3))) void*)(Bs + base), 16, 0, 0);
    }
    __syncthreads();
    #pragma unroll
    for (int kk = 0; kk < 2; ++kk){
      i32x4 a[4], b[4];
      const int cb = kk * 64 + ((lane >> 4) << 4);
      #pragma unroll
      for (int m = 0; m < 4; ++m){
        const int rl = wm * 64 + m * 16 + (lane & 15);
        a[m] = *(const i32x4*)(As + rl * 128 + (cb ^ ((rl & 7) << 4)));
      }
      #pragma unroll
      for (int n = 0; n < 4; ++n){
        const int rl = wn * 64 + n * 16 + (lane & 15);
        b[n] = *(const i32x4*)(Bs + rl * 128 + (cb ^ ((rl & 7) << 4)));
      }
      #pragma unroll
      for (int m = 0; m < 4; ++m)
        #pragma unroll
        for (int n = 0; n < 4; ++n)
          acc[m][n] = __builtin_amdgcn_mfma_i32_16x16x64_i8(a[m], b[n], acc[m][n], 0, 0, 0);
    }
    __syncthreads();
  }

  // epilogue: sim = acc * sc[col] * sx[row]; per-16col maxes; bf16 store
  float scv[4];
  #pragma unroll
  for (int n = 0; n < 4; ++n)
    scv[n] = sc[n0 + wn * 64 + n * 16 + (lane & 15)];
  const int rbase = m0 + wm * 64 + ((lane >> 4) << 2);
  const int blk0  = (n0 >> 4) + wn * 4;
  #pragma unroll
  for (int m = 0; m < 4; ++m){
    #pragma unroll
    for (int rg = 0; rg < 4; ++rg){
      const int row = rbase + m * 16 + rg;
      const float sxr = sx[row];
      const float s0 = (float)acc[m][0][rg] * scv[0] * sxr;
      const float s1 = (float)acc[m][1][rg] * scv[1] * sxr;
      const float s2 = (float)acc[m][2][rg] * scv[2] * sxr;
      const float s3 = (float)acc[m][3][rg] * scv[3] * sxr;
      const float a  = (lane & 1) ? s0 : s1;
      const float b  = (lane & 1) ? s2 : s3;
      const float ra = __shfl_xor(a, 1);
      const float rb = __shfl_xor(b, 1);
      const float u  = (lane & 1) ? fmaxf(s1, ra) : fmaxf(s0, ra);
      const float v  = (lane & 1) ? fmaxf(s3, rb) : fmaxf(s2, rb);
      const float c  = (lane & 2) ? u : v;
      const float rc = __shfl_xor(c, 2);
      float wv = fmaxf((lane & 2) ? v : u, rc);
      wv = fmaxf(wv, __shfl_xor(wv, 4));
      wv = fmaxf(wv, __shfl_xor(wv, 8));
      if ((lane & 15) < 4){
        bm16[(size_t)row * 512 + blk0 + (lane & 3)] = f2bf(wv);
      }
    }
  }
}

// ---------------- per-row candidate extraction -> per-block row lists --------
__global__ __launch_bounds__(256)
void cand_k(const unsigned short* __restrict__ bm16, int* __restrict__ cnt,
            int* __restrict__ list){
  const int r    = blockIdx.x * 4 + (threadIdx.x >> 6);
  const int lane = threadIdx.x & 63;
  const ushort4 q0 = ((const ushort4*)(bm16 + (size_t)r * 512))[lane];
  const ushort4 q1 = ((const ushort4*)(bm16 + (size_t)r * 512))[lane + 64];
  float v[8];
  v[0]=bf2f(q0.x); v[1]=bf2f(q0.y); v[2]=bf2f(q0.z); v[3]=bf2f(q0.w);
  v[4]=bf2f(q1.x); v[5]=bf2f(q1.y); v[6]=bf2f(q1.z); v[7]=bf2f(q1.w);
  float m = v[0];
  #pragma unroll
  for (int k = 1; k < 8; ++k) m = fmaxf(m, v[k]);
  #pragma unroll
  for (int off = 1; off < 64; off <<= 1) m = fmaxf(m, __shfl_xor(m, off));
  const float thr = m - MARGIN;
  #pragma unroll
  for (int k = 0; k < 8; ++k){
    if (v[k] >= thr){
      const int blk = (k < 4) ? (lane * 4 + k) : ((lane + 64) * 4 + (k - 4));
      const int s = atomicAdd(&cnt[blk], 1);
      if (s < CAP) list[blk * CAP + s] = r;
    }
  }
}

// ---------------- codebook-stationary fp32 rescore from lists ----------------
__global__ __launch_bounds__(256, 2)
void rescore_k(const float* __restrict__ X, const float* __restrict__ Cb,
               const float* __restrict__ rn, const int* __restrict__ cnt,
               const int* __restrict__ list, unsigned long long* __restrict__ keys){
  __shared__ float cbs[16 * EMB];   // 48 KB
  __shared__ float rns[16];
  const int g    = blockIdx.x >> 1;      // 16-col block 0..511
  const int half = blockIdx.x & 1;
  const int tid = threadIdx.x;
  const int lane = tid & 63;
  const int w = tid >> 6;

  for (int i = tid; i < 16 * EMB / 4; i += 256)
    ((float4*)cbs)[i] = ((const float4*)(Cb + (size_t)g * 16 * EMB))[i];
  if (tid < 16) rns[tid] = rn[g * 16 + tid];
  __syncthreads();

  const int nc = min(cnt[g], CAP);
  const float4* cbs4 = (const float4*)cbs;
  for (int ci = half * 4 + w; ci < nc; ci += 8){
    const int r = list[g * CAP + ci];
    const float4* x4 = (const float4*)(X + (size_t)r * EMB);
    const float4 x0 = x4[lane], x1 = x4[lane + 64], x2 = x4[lane + 128];
    float best = -3.0e38f; int bc = 0;
    #pragma unroll
    for (int c = 0; c < 16; ++c){
      const float4 c0 = cbs4[c * 192 + lane];
      const float4 c1 = cbs4[c * 192 + lane + 64];
      const float4 c2 = cbs4[c * 192 + lane + 128];
      float s = 0.f;
      s = fmaf(x0.x, c0.x, s); s = fmaf(x0.y, c0.y, s);
      s = fmaf(x0.z, c0.z, s); s = fmaf(x0.w, c0.w, s);
      s = fmaf(x1.x, c1.x, s); s = fmaf(x1.y, c1.y, s);
      s = fmaf(x1.z, c1.z, s); s = fmaf(x1.w, c1.w, s);
      s = fmaf(x2.x, c2.x, s); s = fmaf(x2.y, c2.y, s);
      s = fmaf(x2.z, c2.z, s); s = fmaf(x2.w, c2.w, s);
      #pragma unroll
      for (int off = 1; off < 64; off <<= 1) s += __shfl_xor(s, off);
      s *= rns[c];
      if (s > best){ best = s; bc = c; }     // strict > : first index within block
    }
    if (lane == 0){
      const int col = g * 16 + bc;
      const unsigned long long key =
          ((unsigned long long)fenc(best) << 32) | (unsigned)(8191 - col);
      atomicMax(&keys[r], key);
    }
  }
}

// ---------------- gather + output + per-row loss (one wave per row) ----------
__global__ __launch_bounds__(256)
void writer_k(const float* __restrict__ X, const float* __restrict__ Cb,
              const unsigned long long* __restrict__ keys,
              float* __restrict__ out, float* __restrict__ rowloss){
  const int r    = (blockIdx.x * 256 + threadIdx.x) >> 6;   // one wave per row
  const int lane = threadIdx.x & 63;
  const int idx = 8191 - (int)(unsigned)(keys[r] & 0xFFFFFFFFull);
  const float4* q = (const float4*)(Cb + (size_t)idx * EMB);
  const float4* x = (const float4*)(X + (size_t)r * EMB);
  float4* o = (float4*)(out + (size_t)r * EMB);
  float s = 0.f;
  #pragma unroll
  for (int j = 0; j < 3; ++j){
    const float4 qv = q[lane + 64 * j];
    const float4 xv = x[lane + 64 * j];
    float4 ov;
    float dx = qv.x - xv.x, dy = qv.y - xv.y, dz = qv.z - xv.z, dw = qv.w - xv.w;
    ov.x = xv.x + dx; ov.y = xv.y + dy; ov.z = xv.z + dz; ov.w = xv.w + dw;
    o[lane + 64 * j] = ov;
    s = fmaf(dx, dx, fmaf(dy, dy, fmaf(dz, dz, fmaf(dw, dw, s))));
  }
  #pragma unroll
  for (int off = 1; off < 64; off <<= 1) s += __shfl_xor(s, off);
  if (lane == 0) rowloss[r] = s;
}

// ---------------- deterministic loss finalize (1024 threads) ----------------
__global__ __launch_bounds__(1024)
void finalize_k(const float* __restrict__ rowloss, float* __restrict__ loss_out){
  __shared__ double red[1024];
  const int tid = threadIdx.x;
  double s = 0.0;
  for (int i = tid; i < NB; i += 1024) s += (double)rowloss[i];
  red[tid] = s; __syncthreads();
  for (int off = 512; off > 0; off >>= 1){
    if (tid < off) red[tid] += red[tid + off];
    __syncthreads();
  }
  if (tid == 0)
    loss_out[0] = (float)(1.25 * red[0] / ((double)NB * (double)EMB));
}

extern "C" void kernel_launch(void* const* d_in, const int* in_sizes, int n_in,
                              void* d_out, int out_size, void* d_ws, size_t ws_size,
                              hipStream_t stream){
  const float* X  = (const float*)d_in[0];
  const float* Cb = (const float*)d_in[1];
  float* out = (float*)d_out;

  // i8 staging copies live inside d_out (fully rewritten by writer_k later)
  unsigned char* Xq = (unsigned char*)d_out;                             // 12.6 MB
  unsigned char* Cq = (unsigned char*)d_out + (size_t)NB * EMB;          //  6.3 MB

  char* ws = (char*)d_ws;
  unsigned short* bm16 = (unsigned short*)ws;                          // 16.8 MB
  char* p = ws + (size_t)NB * 512 * 2;
  int* cnt  = (int*)p;                         p += 512 * 4;           // 2 KB
  int* list = (int*)p;                         p += (size_t)512 * CAP * 4; // 4 MB
  unsigned long long* keys = (unsigned long long*)p; p += (size_t)NB * 8;  // 128 KB
  float* rn      = (float*)p;                  p += (size_t)NK * 4;    // 32 KB
  float* rowloss = (float*)p;                  p += (size_t)NB * 4;    // 64 KB
  float* sx      = (float*)p;                  p += (size_t)NB * 4;    // 64 KB
  float* sc      = (float*)p;                                          // 32 KB

  prep_k<<<NB / 4 + NK / 4, 256, 0, stream>>>(X, Cb, Xq, Cq, sx, sc, rn, keys, cnt);
  gemm_bmax_k<<<8192, 256, 0, stream>>>(Xq, Cq, sx, sc, bm16);
  cand_k<<<NB / 4, 256, 0, stream>>>(bm16, cnt, list);
  rescore_k<<<1024, 256, 0, stream>>>(X, Cb, rn, cnt, list, keys);
  writer_k<<<NB / 4, 256, 0, stream>>>(X, Cb, keys, out, rowloss);
  finalize_k<<<1, 1024, 0, stream>>>(rowloss, out + (size_t)NB * EMB);
}